// Round 20
// baseline (776.666 us; speedup 1.0000x reference)
//
#include <hip/hip_runtime.h>
#include <hip/hip_bf16.h>
#include <float.h>

#define BB 8
#define NN 2048
#define KK 20

static constexpr float BN_INV_F = 0.9999950000374997f;  // 1/sqrt(1+1e-5)

typedef __attribute__((ext_vector_type(4))) float f32x4;
typedef __attribute__((ext_vector_type(8))) short s16x8;

__device__ __forceinline__ unsigned short f2bf(float f) {
    __hip_bfloat16 h = __float2bfloat16(f);
    return __builtin_bit_cast(unsigned short, h);
}
__device__ __forceinline__ float bf2f(unsigned short u) {
    unsigned int v = ((unsigned int)u) << 16;
    return __builtin_bit_cast(float, v);
}
// monotone f32 -> u32 (order-preserving)
__device__ __forceinline__ unsigned mono(float f) {
    unsigned b = __builtin_bit_cast(unsigned, f);
    return b ^ (unsigned)(((int)b >> 31) | 0x80000000);
}

// ---------------- f32 -> bf16 cast ----------------
__global__ void cast_bf16_kernel(const float* __restrict__ w, unsigned short* __restrict__ hi, int n) {
    int t = blockIdx.x * blockDim.x + threadIdx.x;
    if (t >= n) return;
    hi[t] = f2bf(w[t]);
}

// ---------------- squared norms ----------------
__global__ void sqnorm_kernel(const float* __restrict__ x, float* __restrict__ xx, int C) {
    int t = blockIdx.x * blockDim.x + threadIdx.x;
    if (t >= BB * NN) return;
    int b = t / NN, n = t % NN;
    const float* xb = x + (size_t)b * C * NN + n;
    float s = 0.f;
    for (int c = 0; c < C; ++c) {
        float v = xb[(size_t)c * NN];
        s += v * v;
    }
    xx[t] = s;
}

// ---------------- pd: pd[b2][n][m] = 2*x_n.x_m - xx[n] - xx[m] (2 batches/chunk) ----
// 8 rows x 1024 cols per block, f32x4 loads/stores (R15-optimal tile).
// Emits per-16-col segment maxima smax[row][128] for topk read-pruning.
__global__ __launch_bounds__(256, 4) void pd_kernel(const float* __restrict__ x,
                                                    const float* __restrict__ xx,
                                                    float* __restrict__ pd,
                                                    float* __restrict__ smax,
                                                    int C, int baseB) {
    __shared__ float ctrT[128][8];   // [c][r]
    __shared__ float xns[8];

    int blk = blockIdx.x;
    int chalf = blk & 1;
    int rt = (blk >> 1) & 255;
    int b2 = blk >> 9;
    int b = baseB + b2;
    int rbase = rt * 8;
    int tid = threadIdx.x;
    const float* xb = x + (size_t)b * C * NN;

    for (int i = tid; i < C * 8; i += 256) {
        int c = i >> 3, r = i & 7;
        ctrT[c][r] = xb[(size_t)c * NN + rbase + r];
    }
    if (tid < 8) xns[tid] = xx[b * NN + rbase + tid];
    __syncthreads();

    int m0 = chalf * 1024 + tid * 4;
    float acc[8][4];
    #pragma unroll
    for (int r = 0; r < 8; ++r)
        #pragma unroll
        for (int j = 0; j < 4; ++j) acc[r][j] = 0.f;

    f32x4 xv = *(const f32x4*)(xb + m0);   // c = 0
    for (int c = 0; c + 1 < C; ++c) {
        f32x4 nxt = *(const f32x4*)(xb + (size_t)(c + 1) * NN + m0);
        f32x4 c0 = *(const f32x4*)&ctrT[c][0];
        f32x4 c1 = *(const f32x4*)&ctrT[c][4];
        #pragma unroll
        for (int j = 0; j < 4; ++j) {
            acc[0][j] += c0.x * xv[j]; acc[1][j] += c0.y * xv[j];
            acc[2][j] += c0.z * xv[j]; acc[3][j] += c0.w * xv[j];
            acc[4][j] += c1.x * xv[j]; acc[5][j] += c1.y * xv[j];
            acc[6][j] += c1.z * xv[j]; acc[7][j] += c1.w * xv[j];
        }
        xv = nxt;
    }
    {
        f32x4 c0 = *(const f32x4*)&ctrT[C - 1][0];
        f32x4 c1 = *(const f32x4*)&ctrT[C - 1][4];
        #pragma unroll
        for (int j = 0; j < 4; ++j) {
            acc[0][j] += c0.x * xv[j]; acc[1][j] += c0.y * xv[j];
            acc[2][j] += c0.z * xv[j]; acc[3][j] += c0.w * xv[j];
            acc[4][j] += c1.x * xv[j]; acc[5][j] += c1.y * xv[j];
            acc[6][j] += c1.z * xv[j]; acc[7][j] += c1.w * xv[j];
        }
    }
    f32x4 xm = *(const f32x4*)(xx + (size_t)b * NN + m0);
    #pragma unroll
    for (int r = 0; r < 8; ++r) {
        f32x4 out;
        #pragma unroll
        for (int j = 0; j < 4; ++j)
            out[j] = 2.f * acc[r][j] - xns[r] - xm[j];
        *(f32x4*)&pd[((size_t)(b2 * NN + rbase + r)) * NN + m0] = out;
        // segment max: 16 cols = 4 consecutive lanes (tid*4 aligned)
        float m4 = fmaxf(fmaxf(out[0], out[1]), fmaxf(out[2], out[3]));
        m4 = fmaxf(m4, __shfl_xor(m4, 1, 64));
        m4 = fmaxf(m4, __shfl_xor(m4, 2, 64));
        if ((tid & 3) == 0)
            smax[((size_t)(b2 * NN + rbase + r)) * 128 + chalf * 64 + (tid >> 2)] = m4;
    }
}

// ---------------- topk v3: segmax-pruned threshold selection, one wave per row ----
__global__ __launch_bounds__(256, 4) void topk_kernel(const float* __restrict__ pd,
                                                      const float* __restrict__ smax,
                                                      int* __restrict__ idxout, int baseB) {
    __shared__ unsigned long long cand[4][128];
    int w = threadIdx.x >> 6, lane = threadIdx.x & 63;
    int rowc = blockIdx.x * 4 + w;                 // 0..4095
    const float* prow = pd + (size_t)rowc * NN;
    const float* srow = smax + (size_t)rowc * 128;

    float sa0 = srow[lane];        // segmax of seg = lane
    float sb0 = srow[64 + lane];   // segmax of seg = 64+lane

    // bitonic sort-128 descending (2 keys/lane) of segment maxima
    float ka = sa0, kb = sb0;
    #pragma unroll
    for (int k = 2; k <= 128; k <<= 1) {
        #pragma unroll
        for (int j = k >> 1; j > 0; j >>= 1) {
            if (j == 64) {                          // only at k=128: intra-lane swap
                float mx = fmaxf(ka, kb), mn = fminf(ka, kb);
                ka = mx; kb = mn;
            } else {
                bool upA, upB;
                if (k == 128)     { upA = true;  upB = true;  }
                else if (k == 64) { upA = true;  upB = false; }
                else              { upA = ((lane & k) == 0); upB = upA; }
                {
                    float o = __shfl_xor(ka, j, 64);
                    bool keepMax = upA ? ((lane & j) == 0) : ((lane & j) != 0);
                    ka = keepMax ? fmaxf(ka, o) : fminf(ka, o);
                }
                {
                    float o = __shfl_xor(kb, j, 64);
                    bool keepMax = upB ? ((lane & j) == 0) : ((lane & j) != 0);
                    kb = keepMax ? fmaxf(kb, o) : fminf(kb, o);
                }
            }
        }
    }
    float Tf = __shfl(ka, KK - 1, 64);             // rank-19 segment max

    cand[w][lane] = 0ull;
    cand[w][64 + lane] = 0ull;
    __builtin_amdgcn_wave_barrier();

    // phase 2: scan only qualifying segments; ballot-compact candidates >= Tf
    int base = 0;
    #pragma unroll
    for (int j = 0; j < 2; ++j) {
        int seg = j * 64 + lane;
        float sm = j ? sb0 : sa0;
        bool active = sm >= Tf;
        f32x4 v0 = { -FLT_MAX, -FLT_MAX, -FLT_MAX, -FLT_MAX };
        f32x4 v1 = v0, v2 = v0, v3 = v0;
        if (active) {
            const float* sp = prow + seg * 16;
            v0 = *(const f32x4*)(sp);
            v1 = *(const f32x4*)(sp + 4);
            v2 = *(const f32x4*)(sp + 8);
            v3 = *(const f32x4*)(sp + 12);
        }
        #pragma unroll
        for (int e = 0; e < 16; ++e) {
            float v = (e < 4) ? v0[e] : (e < 8) ? v1[e - 4] : (e < 12) ? v2[e - 8] : v3[e - 12];
            bool c = active && (v >= Tf);
            unsigned long long mask = __ballot(c);
            if (c) {
                int pos = base + (int)__popcll(mask & ((1ull << lane) - 1ull));
                if (pos < 128)
                    cand[w][pos] = ((unsigned long long)mono(v) << 32) | (unsigned)~(seg * 16 + e);
            }
            base += (int)__popcll(mask);
        }
    }
    __builtin_amdgcn_wave_barrier();

    // final sort of candidates; common case M <= 64 (1 key/lane), else 128 (2 keys/lane)
    unsigned long long qa = cand[w][lane];
    auto cmpx = [&](unsigned long long& key, int j, bool up) {
        unsigned long long o = __shfl_xor(key, j, 64);
        bool keepMax = up ? ((lane & j) == 0) : ((lane & j) != 0);
        bool gt = key > o;
        unsigned long long mx = gt ? key : o, mn = gt ? o : key;
        key = keepMax ? mx : mn;
    };
    if (base <= 64) {
        #pragma unroll
        for (int k = 2; k <= 64; k <<= 1)
            #pragma unroll
            for (int j = k >> 1; j > 0; j >>= 1)
                cmpx(qa, j, (lane & k) == 0);
    } else {
        unsigned long long qb = cand[w][64 + lane];
        #pragma unroll
        for (int k = 2; k <= 128; k <<= 1) {
            #pragma unroll
            for (int j = k >> 1; j > 0; j >>= 1) {
                if (j == 64) {
                    unsigned long long mx = qa > qb ? qa : qb;
                    unsigned long long mn = qa > qb ? qb : qa;
                    qa = mx; qb = mn;
                } else {
                    bool upA, upB;
                    if (k == 128)     { upA = true; upB = true; }
                    else if (k == 64) { upA = true; upB = false; }
                    else              { upA = ((lane & k) == 0); upB = upA; }
                    cmpx(qa, j, upA);
                    cmpx(qb, j, upB);
                }
            }
        }
    }

    if (lane < KK) {
        int col = (int)~(unsigned)(qa & 0xFFFFFFFFull);
        int b = baseB + (rowc >> 11);
        int n = rowc & 2047;
        idxout[((size_t)(b * NN + n)) * KK + lane] = col;
    }
}

// ---------------- P/Q GEMM: 4 outputs/block (2x grid vs 8/block, occupancy fix) ----
__global__ __launch_bounds__(256) void pq_gemm_kernel(const float* __restrict__ x,
                                                      const float* __restrict__ w,
                                                      float* __restrict__ Pt, float* __restrict__ Qt,
                                                      int C, int Cout) {
    __shared__ float wPT[128][4];
    __shared__ float wQT[128][4];
    int blk = blockIdx.x;
    int pass = blk & 1;
    int rest = blk >> 1;
    int nog = Cout >> 2;
    int b = rest / nog;
    int obase = (rest % nog) * 4;
    int tid = threadIdx.x;
    const float* xb = x + (size_t)b * C * NN;

    for (int i = tid; i < C * 4; i += 256) {
        int c = i >> 2, r = i & 3;
        wPT[c][r] = w[(size_t)(obase + r) * 2 * C + c];
        wQT[c][r] = w[(size_t)(obase + r) * 2 * C + C + c];
    }
    __syncthreads();

    int m0 = pass * 1024 + tid * 4;
    float aP[4][4], aQ[4][4];
    #pragma unroll
    for (int r = 0; r < 4; ++r)
        #pragma unroll
        for (int j = 0; j < 4; ++j) { aP[r][j] = 0.f; aQ[r][j] = 0.f; }

    for (int c = 0; c < C; ++c) {
        f32x4 xv = *(const f32x4*)(xb + (size_t)c * NN + m0);
        f32x4 p0 = *(const f32x4*)&wPT[c][0];
        f32x4 q0 = *(const f32x4*)&wQT[c][0];
        #pragma unroll
        for (int j = 0; j < 4; ++j) {
            aP[0][j] += p0.x * xv[j]; aP[1][j] += p0.y * xv[j];
            aP[2][j] += p0.z * xv[j]; aP[3][j] += p0.w * xv[j];
            aQ[0][j] += q0.x * xv[j]; aQ[1][j] += q0.y * xv[j];
            aQ[2][j] += q0.z * xv[j]; aQ[3][j] += q0.w * xv[j];
        }
    }
    #pragma unroll
    for (int j = 0; j < 4; ++j) {
        size_t base = ((size_t)b * NN + m0 + j) * Cout + obase;
        f32x4 vP0, vQ0;
        #pragma unroll
        for (int r = 0; r < 4; ++r) { vP0[r] = aP[r][j]; vQ0[r] = aQ[r][j]; }
        *(f32x4*)&Pt[base] = vP0;
        *(f32x4*)&Qt[base] = vQ0;
    }
}

// ---------------- edge max + feature emit (bf16 Fhi only) ----------------
__global__ __launch_bounds__(256) void edge_max_kernel(const float* __restrict__ Pt,
                                                       const float* __restrict__ Qt,
                                                       const int* __restrict__ idx,
                                                       const float* __restrict__ g,
                                                       const float* __restrict__ bt,
                                                       float* __restrict__ xf32,
                                                       unsigned short* __restrict__ Fhi,
                                                       int coff, int Cout) {
    __shared__ int lidx[16][KK];
    int lanesPerN = Cout >> 2;           // 16 / 32 / 64
    int npw = 64 / lanesPerN;            // 4 / 2 / 1
    int nPerBlock = 4 * npw;             // 16 / 8 / 4

    int blk = blockIdx.x;
    int b = blk / (NN / nPerBlock);
    int nbase = (blk % (NN / nPerBlock)) * nPerBlock;
    int tid = threadIdx.x, wid = tid >> 6, lane = tid & 63;

    for (int i = tid; i < nPerBlock * KK; i += 256) {
        int ln = i / KK, k = i % KK;
        lidx[ln][k] = idx[((size_t)(b * NN + nbase + ln)) * KK + k];
    }
    __syncthreads();

    int nsub = lane / lanesPerN;                     // 0..npw-1
    int ol = (lane & (lanesPerN - 1)) * 4;           // o offset, multiple of 4
    int nrow = wid * npw + nsub;                     // lidx row
    int n = nbase + nrow;

    const float* Pb = Pt + (size_t)b * NN * Cout;
    size_t rowbase = (size_t)n * Cout + ol;
    f32x4 Pn = *(const f32x4*)&Pb[rowbase];
    f32x4 Qn = *(const f32x4*)(Qt + (size_t)b * NN * Cout + rowbase);
    f32x4 off4 = Qn - Pn;
    f32x4 sc4 = *(const f32x4*)&g[ol];
    f32x4 bs4 = *(const f32x4*)&bt[ol];
    #pragma unroll
    for (int e = 0; e < 4; ++e) sc4[e] *= BN_INV_F;

    f32x4 mx4 = { -FLT_MAX, -FLT_MAX, -FLT_MAX, -FLT_MAX };
    #pragma unroll 4
    for (int k = 0; k < KK; ++k) {
        int m = lidx[nrow][k];
        f32x4 pv = *(const f32x4*)&Pb[(size_t)m * Cout + ol];
        #pragma unroll
        for (int e = 0; e < 4; ++e) {
            float y = sc4[e] * (pv[e] + off4[e]) + bs4[e];
            y = (y >= 0.f) ? y : 0.2f * y;
            mx4[e] = fmaxf(mx4[e], y);
        }
    }

    if (xf32) {
        #pragma unroll
        for (int e = 0; e < 4; ++e)
            xf32[((size_t)b * Cout + ol + e) * NN + n] = mx4[e];
    }
    size_t fb = ((size_t)b * NN + n) * 512 + coff + ol;
    ushort4 h4;
    #pragma unroll
    for (int e = 0; e < 4; ++e)
        ((unsigned short*)&h4)[e] = f2bf(mx4[e]);
    *(ushort4*)&Fhi[fb] = h4;
}

// ---------------- conv (1024x512): Whi*Fhi pure bf16 MFMA (K=512) ----------------
__global__ __launch_bounds__(256) void conv_mfma_kernel(const unsigned short* __restrict__ Whi,
                                                        const unsigned short* __restrict__ Fhi,
                                                        const float* __restrict__ gc,
                                                        const float* __restrict__ bc,
                                                        float* __restrict__ pmax,
                                                        float* __restrict__ psum) {
    __shared__ unsigned short As[128 * 64] __attribute__((aligned(16)));
    __shared__ unsigned short Bs[128 * 64] __attribute__((aligned(16)));

    int blk0 = blockIdx.x;
    int blk = (blk0 & 7) * 128 + (blk0 >> 3);

    int nt = blk & 15, ot = (blk >> 4) & 7, b = blk >> 7;
    int obase = ot * 128, nbase = nt * 128;
    int tid = threadIdx.x, lane = tid & 63, wid = tid >> 6;
    int wo = wid >> 1, wn = wid & 1;

    f32x4 acc[4][4];
    #pragma unroll
    for (int m = 0; m < 4; ++m)
        #pragma unroll
        for (int q = 0; q < 4; ++q) acc[m][q] = (f32x4){0.f, 0.f, 0.f, 0.f};

    int srow = tid >> 1, sb = (tid & 1) * 4;

    for (int kt = 0; kt < 8; ++kt) {
        int kc = kt * 64;
        const unsigned short* Asrc = Whi + (size_t)obase * 512 + kc;
        const unsigned short* Bsrc = Fhi + ((size_t)b * NN + nbase) * 512 + kc;
        __syncthreads();
        #pragma unroll
        for (int s = 0; s < 4; ++s) {
            int slot = sb + s;
            uint4 av = *(const uint4*)(Asrc + (size_t)srow * 512 + slot * 8);
            *(uint4*)(As + srow * 64 + ((slot ^ (srow & 7)) * 8)) = av;
            uint4 bv = *(const uint4*)(Bsrc + (size_t)srow * 512 + slot * 8);
            *(uint4*)(Bs + srow * 64 + ((slot ^ (srow & 7)) * 8)) = bv;
        }
        __syncthreads();
        #pragma unroll
        for (int ks = 0; ks < 2; ++ks) {
            s16x8 af[4], bf[4];
            #pragma unroll
            for (int m = 0; m < 4; ++m) {
                int r = wo * 64 + m * 16 + (lane & 15);
                int slot = (ks * 4 + (lane >> 4)) ^ (r & 7);
                af[m] = *(const s16x8*)(As + r * 64 + slot * 8);
                int r2 = wn * 64 + m * 16 + (lane & 15);
                int slot2 = (ks * 4 + (lane >> 4)) ^ (r2 & 7);
                bf[m] = *(const s16x8*)(Bs + r2 * 64 + slot2 * 8);
            }
            #pragma unroll
            for (int m = 0; m < 4; ++m)
                #pragma unroll
                for (int q = 0; q < 4; ++q)
                    acc[m][q] = __builtin_amdgcn_mfma_f32_16x16x32_bf16(af[m], bf[q], acc[m][q], 0, 0, 0);
        }
    }

    __syncthreads();
    float* redm = (float*)As;
    float* reds = redm + 256;
    #pragma unroll
    for (int m = 0; m < 4; ++m) {
        #pragma unroll
        for (int rg = 0; rg < 4; ++rg) {
            int olocal = wo * 64 + m * 16 + (lane >> 4) * 4 + rg;
            int o = obase + olocal;
            float scv = gc[o] * BN_INV_F, bsv = bc[o];
            float mx = -FLT_MAX, sm = 0.f;
            #pragma unroll
            for (int q = 0; q < 4; ++q) {
                float y = scv * acc[m][q][rg] + bsv;
                y = (y >= 0.f) ? y : 0.2f * y;
                mx = fmaxf(mx, y);
                sm += y;
            }
            #pragma unroll
            for (int d = 1; d < 16; d <<= 1) {
                mx = fmaxf(mx, __shfl_xor(mx, d, 64));
                sm += __shfl_xor(sm, d, 64);
            }
            if ((lane & 15) == 0) {
                redm[wn * 128 + olocal] = mx;
                reds[wn * 128 + olocal] = sm;
            }
        }
    }
    __syncthreads();
    if (tid < 128) {
        float mx = fmaxf(redm[tid], redm[128 + tid]);
        float sm = reds[tid] + reds[128 + tid];
        size_t base = ((size_t)b * 1024 + obase + tid) * 16 + nt;
        pmax[base] = mx;
        psum[base] = sm;
    }
}

__global__ void pool_reduce_kernel(const float* __restrict__ pmax, const float* __restrict__ psum,
                                   float* __restrict__ x56) {
    int t = blockIdx.x * blockDim.x + threadIdx.x;
    if (t >= BB * 1024) return;
    int b = t >> 10, o = t & 1023;
    float mx = -FLT_MAX, sm = 0.f;
    for (int ch = 0; ch < 16; ++ch) {
        mx = fmaxf(mx, pmax[(size_t)t * 16 + ch]);
        sm += psum[(size_t)t * 16 + ch];
    }
    x56[(size_t)b * 2048 + o] = mx;
    x56[(size_t)b * 2048 + 1024 + o] = sm * (1.0f / 2048.0f);
}

// ---------------- FC: one wave per (b,o) ----------------
__global__ void fc_kernel(const float* __restrict__ in, const float* __restrict__ w,
                          const float* __restrict__ bw, const float* __restrict__ g,
                          const float* __restrict__ bt, float* __restrict__ out,
                          int Cin, int Cout, int mode) {
    int gt = blockIdx.x * blockDim.x + threadIdx.x;
    int wid = gt >> 6;
    int lane = threadIdx.x & 63;
    if (wid >= BB * Cout) return;
    int b = wid / Cout, o = wid % Cout;
    const float* ib = in + (size_t)b * Cin;
    const float* wr = w + (size_t)o * Cin;
    float acc = 0.f;
    for (int c = lane; c < Cin; c += 64) acc += ib[c] * wr[c];
    for (int d = 32; d >= 1; d >>= 1) acc += __shfl_down(acc, d, 64);
    if (lane == 0) {
        float y;
        if (mode == 0)      { y = g[o] * acc * BN_INV_F + bt[o]; y = (y >= 0.f) ? y : 0.2f * y; }
        else if (mode == 1) { float h = acc + bw[o]; y = g[o] * h * BN_INV_F + bt[o]; y = (y >= 0.f) ? y : 0.2f * y; }
        else                { y = acc + bw[o]; }
        out[(size_t)b * Cout + o] = y;
    }
}

extern "C" void kernel_launch(void* const* d_in, const int* in_sizes, int n_in,
                              void* d_out, int out_size, void* d_ws, size_t ws_size,
                              hipStream_t stream) {
    const float* x    = (const float*)d_in[0];
    const float* w1   = (const float*)d_in[1];
    const float* g1   = (const float*)d_in[2];
    const float* b1   = (const float*)d_in[3];
    const float* w2   = (const float*)d_in[4];
    const float* g2   = (const float*)d_in[5];
    const float* b2   = (const float*)d_in[6];
    const float* w3   = (const float*)d_in[7];
    const float* g3   = (const float*)d_in[8];
    const float* b3   = (const float*)d_in[9];
    const float* w4   = (const float*)d_in[10];
    const float* g4   = (const float*)d_in[11];
    const float* b4   = (const float*)d_in[12];
    const float* wc   = (const float*)d_in[13];
    const float* gc   = (const float*)d_in[14];
    const float* bc   = (const float*)d_in[15];
    const float* wf1  = (const float*)d_in[16];
    const float* gf1  = (const float*)d_in[17];
    const float* bf1  = (const float*)d_in[18];
    const float* wf2  = (const float*)d_in[19];
    const float* bwf2 = (const float*)d_in[20];
    const float* gf2  = (const float*)d_in[21];
    const float* bf2  = (const float*)d_in[22];
    const float* wf3  = (const float*)d_in[23];
    const float* bwf3 = (const float*)d_in[24];

    char* ws = (char*)d_ws;
    size_t off = 0;
    auto alloc = [&](size_t nbytes) {
        char* p = ws + off;
        off += (nbytes + 255) & ~(size_t)255;
        return p;
    };
    float* xx   = (float*)alloc((size_t)BB * NN * 4);
    int*   idx  = (int*)  alloc((size_t)BB * NN * KK * 4);
    float* Pt   = (float*)alloc((size_t)BB * NN * 256 * 4);   // also aliased as pd chunk buffer
    float* Qt   = (float*)alloc((size_t)BB * NN * 256 * 4);
    float* smax = (float*)alloc((size_t)2 * NN * 128 * 4);    // 2 MB per-chunk segment maxima
    float* x1   = (float*)alloc((size_t)BB * 64 * NN * 4);
    float* x2   = (float*)alloc((size_t)BB * 64 * NN * 4);
    float* x3   = (float*)alloc((size_t)BB * 128 * NN * 4);
    unsigned short* Fhi = (unsigned short*)alloc((size_t)BB * NN * 512 * 2);
    unsigned short* Whi = (unsigned short*)alloc((size_t)1024 * 512 * 2);
    float* pmax = (float*)alloc((size_t)BB * 1024 * 16 * 4);
    float* psum = (float*)alloc((size_t)BB * 1024 * 16 * 4);
    float* x56  = (float*)alloc((size_t)BB * 2048 * 4);
    float* f1   = (float*)alloc((size_t)BB * 512 * 4);
    float* f2   = (float*)alloc((size_t)BB * 256 * 4);

    float* pdbuf = Pt;   // alias: spans Pt+Qt (33.55 MB); lifetimes disjoint within a layer

    cast_bf16_kernel<<<(1024 * 512 + 255) / 256, 256, 0, stream>>>(wc, Whi, 1024 * 512);

    struct Layer { const float* xin; int C; const float* w; const float* g; const float* bt;
                   float* xout; int Cout; int coff; };
    Layer L[4] = {
        { x,  3,   w1, g1, b1, x1,      64,  0   },
        { x1, 64,  w2, g2, b2, x2,      64,  64  },
        { x2, 64,  w3, g3, b3, x3,      128, 128 },
        { x3, 128, w4, g4, b4, nullptr, 256, 256 },
    };

    for (int l = 0; l < 4; ++l) {
        sqnorm_kernel<<<(BB * NN) / 256, 256, 0, stream>>>(L[l].xin, xx, L[l].C);
        for (int ch = 0; ch < 4; ++ch) {
            pd_kernel<<<1024, 256, 0, stream>>>(L[l].xin, xx, pdbuf, smax, L[l].C, ch * 2);
            topk_kernel<<<1024, 256, 0, stream>>>(pdbuf, smax, idx, ch * 2);
        }
        pq_gemm_kernel<<<BB * (L[l].Cout / 4) * 2, 256, 0, stream>>>(L[l].xin, L[l].w, Pt, Qt, L[l].C, L[l].Cout);
        int nPerBlock = 4 * (64 / (L[l].Cout >> 2));
        edge_max_kernel<<<BB * (NN / nPerBlock), 256, 0, stream>>>(Pt, Qt, idx, L[l].g, L[l].bt,
                                                                   L[l].xout, Fhi, L[l].coff, L[l].Cout);
    }

    conv_mfma_kernel<<<BB * 8 * 16, 256, 0, stream>>>(Whi, Fhi, gc, bc, pmax, psum);
    pool_reduce_kernel<<<(BB * 1024 + 255) / 256, 256, 0, stream>>>(pmax, psum, x56);
    fc_kernel<<<(BB * 512 * 64 + 255) / 256, 256, 0, stream>>>(x56, wf1, nullptr, gf1, bf1, f1, 2048, 512, 0);
    fc_kernel<<<(BB * 256 * 64 + 255) / 256, 256, 0, stream>>>(f1, wf2, bwf2, gf2, bf2, f2, 512, 256, 1);
    fc_kernel<<<(BB * 40 * 64 + 255) / 256, 256, 0, stream>>>(f2, wf3, bwf3, nullptr, nullptr, (float*)d_out, 256, 40, 2);
}

// Round 21
// 770.459 us; speedup vs baseline: 1.0081x; 1.0081x over previous
//
#include <hip/hip_runtime.h>
#include <hip/hip_bf16.h>
#include <float.h>

#define BB 8
#define NN 2048
#define KK 20

static constexpr float BN_INV_F = 0.9999950000374997f;  // 1/sqrt(1+1e-5)

typedef __attribute__((ext_vector_type(4))) float f32x4;
typedef __attribute__((ext_vector_type(8))) short s16x8;

__device__ __forceinline__ unsigned short f2bf(float f) {
    __hip_bfloat16 h = __float2bfloat16(f);
    return __builtin_bit_cast(unsigned short, h);
}
__device__ __forceinline__ float bf2f(unsigned short u) {
    unsigned int v = ((unsigned int)u) << 16;
    return __builtin_bit_cast(float, v);
}
// monotone f32 -> u32 (order-preserving)
__device__ __forceinline__ unsigned mono(float f) {
    unsigned b = __builtin_bit_cast(unsigned, f);
    return b ^ (unsigned)(((int)b >> 31) | 0x80000000);
}

// ---------------- f32 -> bf16 cast ----------------
__global__ void cast_bf16_kernel(const float* __restrict__ w, unsigned short* __restrict__ hi, int n) {
    int t = blockIdx.x * blockDim.x + threadIdx.x;
    if (t >= n) return;
    hi[t] = f2bf(w[t]);
}

// ---------------- squared norms ----------------
__global__ void sqnorm_kernel(const float* __restrict__ x, float* __restrict__ xx, int C) {
    int t = blockIdx.x * blockDim.x + threadIdx.x;
    if (t >= BB * NN) return;
    int b = t / NN, n = t % NN;
    const float* xb = x + (size_t)b * C * NN + n;
    float s = 0.f;
    for (int c = 0; c < C; ++c) {
        float v = xb[(size_t)c * NN];
        s += v * v;
    }
    xx[t] = s;
}

// ---------------- pd: pd[b2][n][m] = 2*x_n.x_m - xx[n] - xx[m] (2 batches/chunk) ----
// 8 rows x 1024 cols per block, f32x4 loads/stores (R15-optimal tile).
// Emits per-16-col segment maxima smax[row][128] for topk read-pruning.
__global__ __launch_bounds__(256, 4) void pd_kernel(const float* __restrict__ x,
                                                    const float* __restrict__ xx,
                                                    float* __restrict__ pd,
                                                    float* __restrict__ smax,
                                                    int C, int baseB) {
    __shared__ float ctrT[128][8];   // [c][r]
    __shared__ float xns[8];

    int blk = blockIdx.x;
    int chalf = blk & 1;
    int rt = (blk >> 1) & 255;
    int b2 = blk >> 9;
    int b = baseB + b2;
    int rbase = rt * 8;
    int tid = threadIdx.x;
    const float* xb = x + (size_t)b * C * NN;

    for (int i = tid; i < C * 8; i += 256) {
        int c = i >> 3, r = i & 7;
        ctrT[c][r] = xb[(size_t)c * NN + rbase + r];
    }
    if (tid < 8) xns[tid] = xx[b * NN + rbase + tid];
    __syncthreads();

    int m0 = chalf * 1024 + tid * 4;
    float acc[8][4];
    #pragma unroll
    for (int r = 0; r < 8; ++r)
        #pragma unroll
        for (int j = 0; j < 4; ++j) acc[r][j] = 0.f;

    f32x4 xv = *(const f32x4*)(xb + m0);   // c = 0
    for (int c = 0; c + 1 < C; ++c) {
        f32x4 nxt = *(const f32x4*)(xb + (size_t)(c + 1) * NN + m0);
        f32x4 c0 = *(const f32x4*)&ctrT[c][0];
        f32x4 c1 = *(const f32x4*)&ctrT[c][4];
        #pragma unroll
        for (int j = 0; j < 4; ++j) {
            acc[0][j] += c0.x * xv[j]; acc[1][j] += c0.y * xv[j];
            acc[2][j] += c0.z * xv[j]; acc[3][j] += c0.w * xv[j];
            acc[4][j] += c1.x * xv[j]; acc[5][j] += c1.y * xv[j];
            acc[6][j] += c1.z * xv[j]; acc[7][j] += c1.w * xv[j];
        }
        xv = nxt;
    }
    {
        f32x4 c0 = *(const f32x4*)&ctrT[C - 1][0];
        f32x4 c1 = *(const f32x4*)&ctrT[C - 1][4];
        #pragma unroll
        for (int j = 0; j < 4; ++j) {
            acc[0][j] += c0.x * xv[j]; acc[1][j] += c0.y * xv[j];
            acc[2][j] += c0.z * xv[j]; acc[3][j] += c0.w * xv[j];
            acc[4][j] += c1.x * xv[j]; acc[5][j] += c1.y * xv[j];
            acc[6][j] += c1.z * xv[j]; acc[7][j] += c1.w * xv[j];
        }
    }
    f32x4 xm = *(const f32x4*)(xx + (size_t)b * NN + m0);
    #pragma unroll
    for (int r = 0; r < 8; ++r) {
        f32x4 out;
        #pragma unroll
        for (int j = 0; j < 4; ++j)
            out[j] = 2.f * acc[r][j] - xns[r] - xm[j];
        *(f32x4*)&pd[((size_t)(b2 * NN + rbase + r)) * NN + m0] = out;
        // segment max: 16 cols = 4 consecutive lanes (tid*4 aligned)
        float m4 = fmaxf(fmaxf(out[0], out[1]), fmaxf(out[2], out[3]));
        m4 = fmaxf(m4, __shfl_xor(m4, 1, 64));
        m4 = fmaxf(m4, __shfl_xor(m4, 2, 64));
        if ((tid & 3) == 0)
            smax[((size_t)(b2 * NN + rbase + r)) * 128 + chalf * 64 + (tid >> 2)] = m4;
    }
}

// ---------------- topk v3: segmax-pruned threshold selection, one wave per row ----
__global__ __launch_bounds__(256, 4) void topk_kernel(const float* __restrict__ pd,
                                                      const float* __restrict__ smax,
                                                      int* __restrict__ idxout, int baseB) {
    __shared__ unsigned long long cand[4][128];
    int w = threadIdx.x >> 6, lane = threadIdx.x & 63;
    int rowc = blockIdx.x * 4 + w;                 // 0..4095
    const float* prow = pd + (size_t)rowc * NN;
    const float* srow = smax + (size_t)rowc * 128;

    float sa0 = srow[lane];        // segmax of seg = lane
    float sb0 = srow[64 + lane];   // segmax of seg = 64+lane

    // bitonic sort-128 descending (2 keys/lane) of segment maxima
    float ka = sa0, kb = sb0;
    #pragma unroll
    for (int k = 2; k <= 128; k <<= 1) {
        #pragma unroll
        for (int j = k >> 1; j > 0; j >>= 1) {
            if (j == 64) {                          // only at k=128: intra-lane swap
                float mx = fmaxf(ka, kb), mn = fminf(ka, kb);
                ka = mx; kb = mn;
            } else {
                bool upA, upB;
                if (k == 128)     { upA = true;  upB = true;  }
                else if (k == 64) { upA = true;  upB = false; }
                else              { upA = ((lane & k) == 0); upB = upA; }
                {
                    float o = __shfl_xor(ka, j, 64);
                    bool keepMax = upA ? ((lane & j) == 0) : ((lane & j) != 0);
                    ka = keepMax ? fmaxf(ka, o) : fminf(ka, o);
                }
                {
                    float o = __shfl_xor(kb, j, 64);
                    bool keepMax = upB ? ((lane & j) == 0) : ((lane & j) != 0);
                    kb = keepMax ? fmaxf(kb, o) : fminf(kb, o);
                }
            }
        }
    }
    float Tf = __shfl(ka, KK - 1, 64);             // rank-19 segment max

    cand[w][lane] = 0ull;
    cand[w][64 + lane] = 0ull;
    __builtin_amdgcn_wave_barrier();

    // phase 2: scan only qualifying segments; ballot-compact candidates >= Tf
    int base = 0;
    #pragma unroll
    for (int j = 0; j < 2; ++j) {
        int seg = j * 64 + lane;
        float sm = j ? sb0 : sa0;
        bool active = sm >= Tf;
        f32x4 v0 = { -FLT_MAX, -FLT_MAX, -FLT_MAX, -FLT_MAX };
        f32x4 v1 = v0, v2 = v0, v3 = v0;
        if (active) {
            const float* sp = prow + seg * 16;
            v0 = *(const f32x4*)(sp);
            v1 = *(const f32x4*)(sp + 4);
            v2 = *(const f32x4*)(sp + 8);
            v3 = *(const f32x4*)(sp + 12);
        }
        #pragma unroll
        for (int e = 0; e < 16; ++e) {
            float v = (e < 4) ? v0[e] : (e < 8) ? v1[e - 4] : (e < 12) ? v2[e - 8] : v3[e - 12];
            bool c = active && (v >= Tf);
            unsigned long long mask = __ballot(c);
            if (c) {
                int pos = base + (int)__popcll(mask & ((1ull << lane) - 1ull));
                if (pos < 128)
                    cand[w][pos] = ((unsigned long long)mono(v) << 32) | (unsigned)~(seg * 16 + e);
            }
            base += (int)__popcll(mask);
        }
    }
    __builtin_amdgcn_wave_barrier();

    // final sort of candidates; common case M <= 64 (1 key/lane), else 128 (2 keys/lane)
    unsigned long long qa = cand[w][lane];
    auto cmpx = [&](unsigned long long& key, int j, bool up) {
        unsigned long long o = __shfl_xor(key, j, 64);
        bool keepMax = up ? ((lane & j) == 0) : ((lane & j) != 0);
        bool gt = key > o;
        unsigned long long mx = gt ? key : o, mn = gt ? o : key;
        key = keepMax ? mx : mn;
    };
    if (base <= 64) {
        #pragma unroll
        for (int k = 2; k <= 64; k <<= 1)
            #pragma unroll
            for (int j = k >> 1; j > 0; j >>= 1)
                cmpx(qa, j, (lane & k) == 0);
    } else {
        unsigned long long qb = cand[w][64 + lane];
        #pragma unroll
        for (int k = 2; k <= 128; k <<= 1) {
            #pragma unroll
            for (int j = k >> 1; j > 0; j >>= 1) {
                if (j == 64) {
                    unsigned long long mx = qa > qb ? qa : qb;
                    unsigned long long mn = qa > qb ? qb : qa;
                    qa = mx; qb = mn;
                } else {
                    bool upA, upB;
                    if (k == 128)     { upA = true; upB = true; }
                    else if (k == 64) { upA = true; upB = false; }
                    else              { upA = ((lane & k) == 0); upB = upA; }
                    cmpx(qa, j, upA);
                    cmpx(qb, j, upB);
                }
            }
        }
    }

    if (lane < KK) {
        int col = (int)~(unsigned)(qa & 0xFFFFFFFFull);
        int b = baseB + (rowc >> 11);
        int n = rowc & 2047;
        idxout[((size_t)(b * NN + n)) * KK + lane] = col;
    }
}

// ---------------- P/Q GEMM: 8 outputs/block (R19 form; 32B write granularity) ----
__global__ __launch_bounds__(256) void pq_gemm_kernel(const float* __restrict__ x,
                                                      const float* __restrict__ w,
                                                      float* __restrict__ Pt, float* __restrict__ Qt,
                                                      int C, int Cout) {
    __shared__ float wPT[128][8];
    __shared__ float wQT[128][8];
    int blk = blockIdx.x;
    int pass = blk & 1;
    int rest = blk >> 1;
    int nog = Cout >> 3;
    int b = rest / nog;
    int obase = (rest % nog) * 8;
    int tid = threadIdx.x;
    const float* xb = x + (size_t)b * C * NN;

    for (int i = tid; i < C * 8; i += 256) {
        int c = i >> 3, r = i & 7;
        wPT[c][r] = w[(size_t)(obase + r) * 2 * C + c];
        wQT[c][r] = w[(size_t)(obase + r) * 2 * C + C + c];
    }
    __syncthreads();

    int m0 = pass * 1024 + tid * 4;
    float aP[8][4], aQ[8][4];
    #pragma unroll
    for (int r = 0; r < 8; ++r)
        #pragma unroll
        for (int j = 0; j < 4; ++j) { aP[r][j] = 0.f; aQ[r][j] = 0.f; }

    for (int c = 0; c < C; ++c) {
        f32x4 xv = *(const f32x4*)(xb + (size_t)c * NN + m0);
        f32x4 p0 = *(const f32x4*)&wPT[c][0];
        f32x4 p1 = *(const f32x4*)&wPT[c][4];
        f32x4 q0 = *(const f32x4*)&wQT[c][0];
        f32x4 q1 = *(const f32x4*)&wQT[c][4];
        #pragma unroll
        for (int j = 0; j < 4; ++j) {
            aP[0][j] += p0.x * xv[j]; aP[1][j] += p0.y * xv[j];
            aP[2][j] += p0.z * xv[j]; aP[3][j] += p0.w * xv[j];
            aP[4][j] += p1.x * xv[j]; aP[5][j] += p1.y * xv[j];
            aP[6][j] += p1.z * xv[j]; aP[7][j] += p1.w * xv[j];
            aQ[0][j] += q0.x * xv[j]; aQ[1][j] += q0.y * xv[j];
            aQ[2][j] += q0.z * xv[j]; aQ[3][j] += q0.w * xv[j];
            aQ[4][j] += q1.x * xv[j]; aQ[5][j] += q1.y * xv[j];
            aQ[6][j] += q1.z * xv[j]; aQ[7][j] += q1.w * xv[j];
        }
    }
    #pragma unroll
    for (int j = 0; j < 4; ++j) {
        size_t base = ((size_t)b * NN + m0 + j) * Cout + obase;
        f32x4 vP0, vP1, vQ0, vQ1;
        #pragma unroll
        for (int r = 0; r < 4; ++r) { vP0[r] = aP[r][j]; vP1[r] = aP[r + 4][j];
                                      vQ0[r] = aQ[r][j]; vQ1[r] = aQ[r + 4][j]; }
        *(f32x4*)&Pt[base] = vP0; *(f32x4*)&Pt[base + 4] = vP1;
        *(f32x4*)&Qt[base] = vQ0; *(f32x4*)&Qt[base + 4] = vQ1;
    }
}

// ---------------- edge max + feature emit (bf16 Fhi only) ----------------
__global__ __launch_bounds__(256) void edge_max_kernel(const float* __restrict__ Pt,
                                                       const float* __restrict__ Qt,
                                                       const int* __restrict__ idx,
                                                       const float* __restrict__ g,
                                                       const float* __restrict__ bt,
                                                       float* __restrict__ xf32,
                                                       unsigned short* __restrict__ Fhi,
                                                       int coff, int Cout) {
    __shared__ int lidx[16][KK];
    int lanesPerN = Cout >> 2;           // 16 / 32 / 64
    int npw = 64 / lanesPerN;            // 4 / 2 / 1
    int nPerBlock = 4 * npw;             // 16 / 8 / 4

    int blk = blockIdx.x;
    int b = blk / (NN / nPerBlock);
    int nbase = (blk % (NN / nPerBlock)) * nPerBlock;
    int tid = threadIdx.x, wid = tid >> 6, lane = tid & 63;

    for (int i = tid; i < nPerBlock * KK; i += 256) {
        int ln = i / KK, k = i % KK;
        lidx[ln][k] = idx[((size_t)(b * NN + nbase + ln)) * KK + k];
    }
    __syncthreads();

    int nsub = lane / lanesPerN;                     // 0..npw-1
    int ol = (lane & (lanesPerN - 1)) * 4;           // o offset, multiple of 4
    int nrow = wid * npw + nsub;                     // lidx row
    int n = nbase + nrow;

    const float* Pb = Pt + (size_t)b * NN * Cout;
    size_t rowbase = (size_t)n * Cout + ol;
    f32x4 Pn = *(const f32x4*)&Pb[rowbase];
    f32x4 Qn = *(const f32x4*)(Qt + (size_t)b * NN * Cout + rowbase);
    f32x4 off4 = Qn - Pn;
    f32x4 sc4 = *(const f32x4*)&g[ol];
    f32x4 bs4 = *(const f32x4*)&bt[ol];
    #pragma unroll
    for (int e = 0; e < 4; ++e) sc4[e] *= BN_INV_F;

    f32x4 mx4 = { -FLT_MAX, -FLT_MAX, -FLT_MAX, -FLT_MAX };
    #pragma unroll 4
    for (int k = 0; k < KK; ++k) {
        int m = lidx[nrow][k];
        f32x4 pv = *(const f32x4*)&Pb[(size_t)m * Cout + ol];
        #pragma unroll
        for (int e = 0; e < 4; ++e) {
            float y = sc4[e] * (pv[e] + off4[e]) + bs4[e];
            y = (y >= 0.f) ? y : 0.2f * y;
            mx4[e] = fmaxf(mx4[e], y);
        }
    }

    if (xf32) {
        #pragma unroll
        for (int e = 0; e < 4; ++e)
            xf32[((size_t)b * Cout + ol + e) * NN + n] = mx4[e];
    }
    size_t fb = ((size_t)b * NN + n) * 512 + coff + ol;
    ushort4 h4;
    #pragma unroll
    for (int e = 0; e < 4; ++e)
        ((unsigned short*)&h4)[e] = f2bf(mx4[e]);
    *(ushort4*)&Fhi[fb] = h4;
}

// ---------------- conv (1024x512): Whi*Fhi pure bf16 MFMA (K=512) ----------------
__global__ __launch_bounds__(256) void conv_mfma_kernel(const unsigned short* __restrict__ Whi,
                                                        const unsigned short* __restrict__ Fhi,
                                                        const float* __restrict__ gc,
                                                        const float* __restrict__ bc,
                                                        float* __restrict__ pmax,
                                                        float* __restrict__ psum) {
    __shared__ unsigned short As[128 * 64] __attribute__((aligned(16)));
    __shared__ unsigned short Bs[128 * 64] __attribute__((aligned(16)));

    int blk0 = blockIdx.x;
    int blk = (blk0 & 7) * 128 + (blk0 >> 3);

    int nt = blk & 15, ot = (blk >> 4) & 7, b = blk >> 7;
    int obase = ot * 128, nbase = nt * 128;
    int tid = threadIdx.x, lane = tid & 63, wid = tid >> 6;
    int wo = wid >> 1, wn = wid & 1;

    f32x4 acc[4][4];
    #pragma unroll
    for (int m = 0; m < 4; ++m)
        #pragma unroll
        for (int q = 0; q < 4; ++q) acc[m][q] = (f32x4){0.f, 0.f, 0.f, 0.f};

    int srow = tid >> 1, sb = (tid & 1) * 4;

    for (int kt = 0; kt < 8; ++kt) {
        int kc = kt * 64;
        const unsigned short* Asrc = Whi + (size_t)obase * 512 + kc;
        const unsigned short* Bsrc = Fhi + ((size_t)b * NN + nbase) * 512 + kc;
        __syncthreads();
        #pragma unroll
        for (int s = 0; s < 4; ++s) {
            int slot = sb + s;
            uint4 av = *(const uint4*)(Asrc + (size_t)srow * 512 + slot * 8);
            *(uint4*)(As + srow * 64 + ((slot ^ (srow & 7)) * 8)) = av;
            uint4 bv = *(const uint4*)(Bsrc + (size_t)srow * 512 + slot * 8);
            *(uint4*)(Bs + srow * 64 + ((slot ^ (srow & 7)) * 8)) = bv;
        }
        __syncthreads();
        #pragma unroll
        for (int ks = 0; ks < 2; ++ks) {
            s16x8 af[4], bf[4];
            #pragma unroll
            for (int m = 0; m < 4; ++m) {
                int r = wo * 64 + m * 16 + (lane & 15);
                int slot = (ks * 4 + (lane >> 4)) ^ (r & 7);
                af[m] = *(const s16x8*)(As + r * 64 + slot * 8);
                int r2 = wn * 64 + m * 16 + (lane & 15);
                int slot2 = (ks * 4 + (lane >> 4)) ^ (r2 & 7);
                bf[m] = *(const s16x8*)(Bs + r2 * 64 + slot2 * 8);
            }
            #pragma unroll
            for (int m = 0; m < 4; ++m)
                #pragma unroll
                for (int q = 0; q < 4; ++q)
                    acc[m][q] = __builtin_amdgcn_mfma_f32_16x16x32_bf16(af[m], bf[q], acc[m][q], 0, 0, 0);
        }
    }

    __syncthreads();
    float* redm = (float*)As;
    float* reds = redm + 256;
    #pragma unroll
    for (int m = 0; m < 4; ++m) {
        #pragma unroll
        for (int rg = 0; rg < 4; ++rg) {
            int olocal = wo * 64 + m * 16 + (lane >> 4) * 4 + rg;
            int o = obase + olocal;
            float scv = gc[o] * BN_INV_F, bsv = bc[o];
            float mx = -FLT_MAX, sm = 0.f;
            #pragma unroll
            for (int q = 0; q < 4; ++q) {
                float y = scv * acc[m][q][rg] + bsv;
                y = (y >= 0.f) ? y : 0.2f * y;
                mx = fmaxf(mx, y);
                sm += y;
            }
            #pragma unroll
            for (int d = 1; d < 16; d <<= 1) {
                mx = fmaxf(mx, __shfl_xor(mx, d, 64));
                sm += __shfl_xor(sm, d, 64);
            }
            if ((lane & 15) == 0) {
                redm[wn * 128 + olocal] = mx;
                reds[wn * 128 + olocal] = sm;
            }
        }
    }
    __syncthreads();
    if (tid < 128) {
        float mx = fmaxf(redm[tid], redm[128 + tid]);
        float sm = reds[tid] + reds[128 + tid];
        size_t base = ((size_t)b * 1024 + obase + tid) * 16 + nt;
        pmax[base] = mx;
        psum[base] = sm;
    }
}

__global__ void pool_reduce_kernel(const float* __restrict__ pmax, const float* __restrict__ psum,
                                   float* __restrict__ x56) {
    int t = blockIdx.x * blockDim.x + threadIdx.x;
    if (t >= BB * 1024) return;
    int b = t >> 10, o = t & 1023;
    float mx = -FLT_MAX, sm = 0.f;
    for (int ch = 0; ch < 16; ++ch) {
        mx = fmaxf(mx, pmax[(size_t)t * 16 + ch]);
        sm += psum[(size_t)t * 16 + ch];
    }
    x56[(size_t)b * 2048 + o] = mx;
    x56[(size_t)b * 2048 + 1024 + o] = sm * (1.0f / 2048.0f);
}

// ---------------- FC: one wave per (b,o) ----------------
__global__ void fc_kernel(const float* __restrict__ in, const float* __restrict__ w,
                          const float* __restrict__ bw, const float* __restrict__ g,
                          const float* __restrict__ bt, float* __restrict__ out,
                          int Cin, int Cout, int mode) {
    int gt = blockIdx.x * blockDim.x + threadIdx.x;
    int wid = gt >> 6;
    int lane = threadIdx.x & 63;
    if (wid >= BB * Cout) return;
    int b = wid / Cout, o = wid % Cout;
    const float* ib = in + (size_t)b * Cin;
    const float* wr = w + (size_t)o * Cin;
    float acc = 0.f;
    for (int c = lane; c < Cin; c += 64) acc += ib[c] * wr[c];
    for (int d = 32; d >= 1; d >>= 1) acc += __shfl_down(acc, d, 64);
    if (lane == 0) {
        float y;
        if (mode == 0)      { y = g[o] * acc * BN_INV_F + bt[o]; y = (y >= 0.f) ? y : 0.2f * y; }
        else if (mode == 1) { float h = acc + bw[o]; y = g[o] * h * BN_INV_F + bt[o]; y = (y >= 0.f) ? y : 0.2f * y; }
        else                { y = acc + bw[o]; }
        out[(size_t)b * Cout + o] = y;
    }
}

extern "C" void kernel_launch(void* const* d_in, const int* in_sizes, int n_in,
                              void* d_out, int out_size, void* d_ws, size_t ws_size,
                              hipStream_t stream) {
    const float* x    = (const float*)d_in[0];
    const float* w1   = (const float*)d_in[1];
    const float* g1   = (const float*)d_in[2];
    const float* b1   = (const float*)d_in[3];
    const float* w2   = (const float*)d_in[4];
    const float* g2   = (const float*)d_in[5];
    const float* b2   = (const float*)d_in[6];
    const float* w3   = (const float*)d_in[7];
    const float* g3   = (const float*)d_in[8];
    const float* b3   = (const float*)d_in[9];
    const float* w4   = (const float*)d_in[10];
    const float* g4   = (const float*)d_in[11];
    const float* b4   = (const float*)d_in[12];
    const float* wc   = (const float*)d_in[13];
    const float* gc   = (const float*)d_in[14];
    const float* bc   = (const float*)d_in[15];
    const float* wf1  = (const float*)d_in[16];
    const float* gf1  = (const float*)d_in[17];
    const float* bf1  = (const float*)d_in[18];
    const float* wf2  = (const float*)d_in[19];
    const float* bwf2 = (const float*)d_in[20];
    const float* gf2  = (const float*)d_in[21];
    const float* bf2  = (const float*)d_in[22];
    const float* wf3  = (const float*)d_in[23];
    const float* bwf3 = (const float*)d_in[24];

    char* ws = (char*)d_ws;
    size_t off = 0;
    auto alloc = [&](size_t nbytes) {
        char* p = ws + off;
        off += (nbytes + 255) & ~(size_t)255;
        return p;
    };
    float* xx   = (float*)alloc((size_t)BB * NN * 4);
    int*   idx  = (int*)  alloc((size_t)BB * NN * KK * 4);
    float* Pt   = (float*)alloc((size_t)BB * NN * 256 * 4);   // also aliased as pd chunk buffer
    float* Qt   = (float*)alloc((size_t)BB * NN * 256 * 4);
    float* smax = (float*)alloc((size_t)2 * NN * 128 * 4);    // 2 MB per-chunk segment maxima
    float* x1   = (float*)alloc((size_t)BB * 64 * NN * 4);
    float* x2   = (float*)alloc((size_t)BB * 64 * NN * 4);
    float* x3   = (float*)alloc((size_t)BB * 128 * NN * 4);
    unsigned short* Fhi = (unsigned short*)alloc((size_t)BB * NN * 512 * 2);
    unsigned short* Whi = (unsigned short*)alloc((size_t)1024 * 512 * 2);
    float* pmax = (float*)alloc((size_t)BB * 1024 * 16 * 4);
    float* psum = (float*)alloc((size_t)BB * 1024 * 16 * 4);
    float* x56  = (float*)alloc((size_t)BB * 2048 * 4);
    float* f1   = (float*)alloc((size_t)BB * 512 * 4);
    float* f2   = (float*)alloc((size_t)BB * 256 * 4);

    float* pdbuf = Pt;   // alias: spans Pt+Qt (33.55 MB); lifetimes disjoint within a layer

    cast_bf16_kernel<<<(1024 * 512 + 255) / 256, 256, 0, stream>>>(wc, Whi, 1024 * 512);

    struct Layer { const float* xin; int C; const float* w; const float* g; const float* bt;
                   float* xout; int Cout; int coff; };
    Layer L[4] = {
        { x,  3,   w1, g1, b1, x1,      64,  0   },
        { x1, 64,  w2, g2, b2, x2,      64,  64  },
        { x2, 64,  w3, g3, b3, x3,      128, 128 },
        { x3, 128, w4, g4, b4, nullptr, 256, 256 },
    };

    for (int l = 0; l < 4; ++l) {
        sqnorm_kernel<<<(BB * NN) / 256, 256, 0, stream>>>(L[l].xin, xx, L[l].C);
        for (int ch = 0; ch < 4; ++ch) {
            pd_kernel<<<1024, 256, 0, stream>>>(L[l].xin, xx, pdbuf, smax, L[l].C, ch * 2);
            topk_kernel<<<1024, 256, 0, stream>>>(pdbuf, smax, idx, ch * 2);
        }
        pq_gemm_kernel<<<BB * (L[l].Cout / 8) * 2, 256, 0, stream>>>(L[l].xin, L[l].w, Pt, Qt, L[l].C, L[l].Cout);
        int nPerBlock = 4 * (64 / (L[l].Cout >> 2));
        edge_max_kernel<<<BB * (NN / nPerBlock), 256, 0, stream>>>(Pt, Qt, idx, L[l].g, L[l].bt,
                                                                   L[l].xout, Fhi, L[l].coff, L[l].Cout);
    }

    conv_mfma_kernel<<<BB * 8 * 16, 256, 0, stream>>>(Whi, Fhi, gc, bc, pmax, psum);
    pool_reduce_kernel<<<(BB * 1024 + 255) / 256, 256, 0, stream>>>(pmax, psum, x56);
    fc_kernel<<<(BB * 512 * 64 + 255) / 256, 256, 0, stream>>>(x56, wf1, nullptr, gf1, bf1, f1, 2048, 512, 0);
    fc_kernel<<<(BB * 256 * 64 + 255) / 256, 256, 0, stream>>>(f1, wf2, bwf2, gf2, bf2, f2, 512, 256, 1);
    fc_kernel<<<(BB * 40 * 64 + 255) / 256, 256, 0, stream>>>(f2, wf3, bwf3, nullptr, nullptr, (float*)d_out, 256, 40, 2);
}